// Round 2
// 687.678 us; speedup vs baseline: 1.0175x; 1.0175x over previous
//
#include <hip/hip_runtime.h>

#define GLOBAL_AS __attribute__((address_space(1)))
#define LDS_AS    __attribute__((address_space(3)))

typedef __bf16 bf16_t;
typedef __bf16 bf16x8 __attribute__((ext_vector_type(8)));
typedef __bf16 bf16x4 __attribute__((ext_vector_type(4)));
typedef float  f32x4  __attribute__((ext_vector_type(4)));

// Problem constants (B=64, S=1024, D=768)
#define BATCH 64
#define SEQ   1024
#define DIM   768
#define BS_ROWS (BATCH * SEQ)            // 65536

__device__ __forceinline__ void gl2lds16(const void* g, void* l) {
    __builtin_amdgcn_global_load_lds((GLOBAL_AS const void*)g, (LDS_AS void*)l, 16, 0, 0);
}

// ---------------- zero fp32 buffer (replaces hipMemsetAsync; capture-safe) --
__global__ void k_zero(float* __restrict__ p, int n) {
    int gid = blockIdx.x * 256 + threadIdx.x;
    if (gid < n) p[gid] = 0.f;
}

// ---------------- fp32 -> bf16 convert (8 elems/thread) ----------------
__global__ void k_convert(const float* __restrict__ x, bf16_t* __restrict__ y, int n8) {
    int gid = blockIdx.x * 256 + threadIdx.x;
    if (gid >= n8) return;
    const float4* xp = (const float4*)x;
    float4 a = xp[gid * 2];
    float4 b = xp[gid * 2 + 1];
    bf16x8 v;
    v[0] = (bf16_t)a.x; v[1] = (bf16_t)a.y; v[2] = (bf16_t)a.z; v[3] = (bf16_t)a.w;
    v[4] = (bf16_t)b.x; v[5] = (bf16_t)b.y; v[6] = (bf16_t)b.z; v[7] = (bf16_t)b.w;
    ((bf16x8*)y)[gid] = v;
}

// ---------------- Asym = A + A^T, cast bf16 ----------------
__global__ void k_asym(const float* __restrict__ A, bf16_t* __restrict__ S_, int n) {
    int idx = blockIdx.x * 256 + threadIdx.x;
    if (idx >= n) return;
    int d = idx / DIM;
    int e = idx - d * DIM;
    S_[idx] = (bf16_t)(A[idx] + A[e * DIM + d]);
}

// ---------------- GEMM1: M = H @ Asym, fused partial q ----------------
// 1D grid of 3072 blocks, XCD-affine swizzle: xcd = g&7 owns a contiguous
// range of row-slabs (A-slab L2 reuse across its 6 col-tiles; Asym resident).
// Epilogue additionally accumulates q[row] = 0.5 * dot(M[row], H[row]) via
// per-fragment shuffle reduce + atomicAdd (H tile is L2-hot: this block just
// streamed those exact rows through LDS).
__global__ void k_gemm1(const bf16_t* __restrict__ H, const bf16_t* __restrict__ Ag,
                        bf16_t* __restrict__ M, float* __restrict__ qv) {
    __shared__ bf16_t Asm[128 * 32];
    __shared__ bf16_t Bsm[128 * 32];
    const int t = threadIdx.x;
    const int g = blockIdx.x;
    const int tile = (g & 7) * 384 + (g >> 3);   // 3072/8 = 384 tiles per XCD
    const int row0 = (tile / 6) * 128;
    const int col0 = (tile % 6) * 128;
    const int ln = t & 63, w = t >> 6;
    const int wr = w >> 1, wc = w & 1;
    const int r = ln & 15, qd = ln >> 4;
    const int sseg = qd ^ ((r >> 1) & 3);      // swizzled read segment

    const int srow = t >> 2;
    const int gseg = (t & 3) ^ ((t >> 3) & 3); // swizzled global segment
    const bf16_t* gA0 = H  + (size_t)(row0 + srow) * DIM + gseg * 8;
    const bf16_t* gA1 = gA0 + (size_t)64 * DIM;
    const bf16_t* gB0 = Ag + (size_t)(col0 + srow) * DIM + gseg * 8;
    const bf16_t* gB1 = gB0 + (size_t)64 * DIM;

    f32x4 acc[4][4] = {};

    for (int k0 = 0; k0 < DIM; k0 += 32) {
        gl2lds16(gA0 + k0, &Asm[t * 8]);
        gl2lds16(gA1 + k0, &Asm[2048 + t * 8]);
        gl2lds16(gB0 + k0, &Bsm[t * 8]);
        gl2lds16(gB1 + k0, &Bsm[2048 + t * 8]);
        __syncthreads();   // drains vmcnt (global_load_lds) before reads

        bf16x8 af[4], bf[4];
#pragma unroll
        for (int mt = 0; mt < 4; ++mt) {
            int m = wr * 64 + mt * 16 + r;
            af[mt] = *(const bf16x8*)&Asm[m * 32 + sseg * 8];
        }
#pragma unroll
        for (int nt = 0; nt < 4; ++nt) {
            int n = wc * 64 + nt * 16 + r;
            bf[nt] = *(const bf16x8*)&Bsm[n * 32 + sseg * 8];
        }
#pragma unroll
        for (int mt = 0; mt < 4; ++mt)
#pragma unroll
            for (int nt = 0; nt < 4; ++nt)
                acc[mt][nt] = __builtin_amdgcn_mfma_f32_16x16x32_bf16(
                    af[mt], bf[nt], acc[mt][nt], 0, 0, 0);
        __syncthreads();
    }

    // epilogue: store M (bf16) + fused partial q.
    // q uses the bf16-ROUNDED M values so q is numerically consistent with
    // gemm2's G (keeps diag dists near 0, same as the old k_q).
#pragma unroll
    for (int mt = 0; mt < 4; ++mt) {
#pragma unroll
        for (int rI = 0; rI < 4; ++rI) {
            int row = row0 + wr * 64 + mt * 16 + qd * 4 + rI;
            size_t base = (size_t)row * DIM + col0 + wc * 64;
            float s = 0.f;
#pragma unroll
            for (int nt = 0; nt < 4; ++nt) {
                bf16_t mv = (bf16_t)acc[mt][nt][rI];
                M[base + nt * 16 + r] = mv;
                s += (float)mv * (float)H[base + nt * 16 + r];
            }
            // reduce across the 16 r-lanes (lane bits 0..3)
            s += __shfl_xor(s, 1, 64);
            s += __shfl_xor(s, 2, 64);
            s += __shfl_xor(s, 4, 64);
            s += __shfl_xor(s, 8, 64);
            if (r == 0) atomicAdd(&qv[row], 0.5f * s);
        }
    }
}

// ---------------- GEMM2: triangular tiles, mirrored write ----------------
// dists is exactly symmetric (G_ij = h_i^T Asym h_j = G_ji), so compute only
// tj >= ti (36 of 64 tiles/batch) and write off-diag tiles twice (the mirror
// goes through a padded LDS transpose so stores stay coalesced).
// 1D grid 2304 = 8 xcd * 8 batches * 36 tiles; each XCD owns 8 whole batches
// so the 3 MB/batch (M_b + H_b) working set stays in its 4 MB L2.
__global__ void k_gemm2(const bf16_t* __restrict__ M, const bf16_t* __restrict__ H,
                        const float* __restrict__ qv, float* __restrict__ out) {
    __shared__ __align__(16) char smem[16640];   // max(2*8192, 32*130*4)
    bf16_t* Asm = (bf16_t*)smem;
    bf16_t* Bsm = (bf16_t*)(smem + 8192);
    float*  Tsm = (float*)smem;                  // 32 x 130 fp32 transpose chunk

    const int t = threadIdx.x;
    const int g = blockIdx.x;                    // 0..2303
    const int u = (g & 7) * 288 + (g >> 3);      // 2304/8 = 288 per XCD
    const int b = u / 36;
    int l = u - b * 36;
    int ti = 0;
    while (l >= 8 - ti) { l -= 8 - ti; ++ti; }   // uniform scalar decode
    const int tj = ti + l;
    const int row0 = ti * 128;
    const int col0 = tj * 128;

    const int ln = t & 63, w = t >> 6;
    const int wr = w >> 1, wc = w & 1;
    const int r = ln & 15, qd = ln >> 4;
    const int sseg = qd ^ ((r >> 1) & 3);

    const bf16_t* Mb = M + (size_t)b * SEQ * DIM;
    const bf16_t* Hb = H + (size_t)b * SEQ * DIM;

    const int srow = t >> 2;
    const int gseg = (t & 3) ^ ((t >> 3) & 3);
    const bf16_t* gA0 = Mb + (size_t)(row0 + srow) * DIM + gseg * 8;
    const bf16_t* gA1 = gA0 + (size_t)64 * DIM;
    const bf16_t* gB0 = Hb + (size_t)(col0 + srow) * DIM + gseg * 8;
    const bf16_t* gB1 = gB0 + (size_t)64 * DIM;

    f32x4 acc[4][4] = {};

    for (int k0 = 0; k0 < DIM; k0 += 32) {
        gl2lds16(gA0 + k0, &Asm[t * 8]);
        gl2lds16(gA1 + k0, &Asm[2048 + t * 8]);
        gl2lds16(gB0 + k0, &Bsm[t * 8]);
        gl2lds16(gB1 + k0, &Bsm[2048 + t * 8]);
        __syncthreads();

        bf16x8 af[4], bf[4];
#pragma unroll
        for (int mt = 0; mt < 4; ++mt) {
            int m = wr * 64 + mt * 16 + r;
            af[mt] = *(const bf16x8*)&Asm[m * 32 + sseg * 8];
        }
#pragma unroll
        for (int nt = 0; nt < 4; ++nt) {
            int n = wc * 64 + nt * 16 + r;
            bf[nt] = *(const bf16x8*)&Bsm[n * 32 + sseg * 8];
        }
#pragma unroll
        for (int mt = 0; mt < 4; ++mt)
#pragma unroll
            for (int nt = 0; nt < 4; ++nt)
                acc[mt][nt] = __builtin_amdgcn_mfma_f32_16x16x32_bf16(
                    af[mt], bf[nt], acc[mt][nt], 0, 0, 0);
        __syncthreads();
    }

    const float* qb = qv + b * SEQ;
    float qc[4];
#pragma unroll
    for (int nt = 0; nt < 4; ++nt) qc[nt] = qb[col0 + wc * 64 + nt * 16 + r];

    // normal (upper) tile write: out[b][row][col]
#pragma unroll
    for (int mt = 0; mt < 4; ++mt) {
#pragma unroll
        for (int rI = 0; rI < 4; ++rI) {
            int row = row0 + wr * 64 + mt * 16 + qd * 4 + rI;
            float qr = qb[row];
            size_t base = ((size_t)b * SEQ + row) * SEQ + col0 + wc * 64;
#pragma unroll
            for (int nt = 0; nt < 4; ++nt)
                out[base + nt * 16 + r] = qr + qc[nt] - acc[mt][nt][rI];
        }
    }

    // mirror (lower) tile write: out[b][col][row], via 4x 32-row LDS chunks.
    // Tsm stride 130 words => both stage-write (8*qd + r pattern) and
    // read (2*lrow + lcol pattern) are <=2-way bank aliasing (free).
    if (ti != tj) {
#pragma unroll
        for (int c = 0; c < 4; ++c) {
            __syncthreads();                    // prev chunk fully consumed
            if (wr == (c >> 1)) {
                const int m0 = (c & 1) * 2;     // compile-time per unrolled c
#pragma unroll
                for (int mi = 0; mi < 2; ++mi) {
                    const int mt = m0 + mi;     // static index into acc
#pragma unroll
                    for (int rI = 0; rI < 4; ++rI) {
                        int lrow = mi * 16 + qd * 4 + rI;          // 0..31
                        int row = row0 + wr * 64 + mt * 16 + qd * 4 + rI;
                        float qr = qb[row];
#pragma unroll
                        for (int nt = 0; nt < 4; ++nt) {
                            int lcol = wc * 64 + nt * 16 + r;
                            Tsm[lrow * 130 + lcol] = qr + qc[nt] - acc[mt][nt][rI];
                        }
                    }
                }
            }
            __syncthreads();
            const int rowbase = row0 + 32 * c;
#pragma unroll
            for (int i = 0; i < 16; ++i) {
                int lin = i * 256 + t;
                int lrow = lin & 31;
                int lcol = lin >> 5;            // 0..127
                out[((size_t)b * SEQ + col0 + lcol) * SEQ + rowbase + lrow] =
                    Tsm[lrow * 130 + lcol];
            }
        }
    }
}

extern "C" void kernel_launch(void* const* d_in, const int* in_sizes, int n_in,
                              void* d_out, int out_size, void* d_ws, size_t ws_size,
                              hipStream_t stream) {
    const float* batch = (const float*)d_in[0];  // (64,1024,768) fp32
    const float* proj  = (const float*)d_in[1];  // (768,768) fp32
    float* out = (float*)d_out;                  // (64,1024,1024) fp32

    char* ws = (char*)d_ws;
    // Workspace layout (all 16B-aligned):
    //   Hb:  BS_ROWS*DIM bf16  = 100663296 B  @ 0
    //   Mb:  BS_ROWS*DIM bf16  = 100663296 B  @ 100663296
    //   Ab:  DIM*DIM bf16      =   1179648 B  @ 201326592
    //   qv:  BS_ROWS fp32      =    262144 B  @ 202506240
    bf16_t* Hb = (bf16_t*)ws;
    bf16_t* Mb = (bf16_t*)(ws + 100663296);
    bf16_t* Ab = (bf16_t*)(ws + 201326592);
    float*  qv = (float*)(ws + 202506240);

    // 0) zero q accumulators (gemm1 epilogue atomically accumulates)
    k_zero<<<256, 256, 0, stream>>>(qv, BS_ROWS);
    // 1) batch -> bf16 (50331648 elems / 8 per thread)
    k_convert<<<24576, 256, 0, stream>>>(batch, Hb, 6291456);
    // 2) Asym = A + A^T in bf16
    k_asym<<<2304, 256, 0, stream>>>(proj, Ab, DIM * DIM);
    // 3) M = H @ Asym + fused q = 0.5*rowdot(M,H)  (65536 x 768, K=768)
    k_gemm1<<<3072, 256, 0, stream>>>(Hb, Ab, Mb, qv);
    // 4) per-batch triangular G = M H^T, dists = q_i + q_j - G, mirrored write
    k_gemm2<<<2304, 256, 0, stream>>>(Mb, Hb, qv, out);
}

// Round 3
// 637.656 us; speedup vs baseline: 1.0973x; 1.0784x over previous
//
#include <hip/hip_runtime.h>

#define GLOBAL_AS __attribute__((address_space(1)))
#define LDS_AS    __attribute__((address_space(3)))

typedef __bf16 bf16_t;
typedef __bf16 bf16x8 __attribute__((ext_vector_type(8)));
typedef float  f32x4  __attribute__((ext_vector_type(4)));

// Problem constants (B=64, S=1024, D=768)
#define BATCH 64
#define SEQ   1024
#define DIM   768
#define BS_ROWS (BATCH * SEQ)            // 65536

__device__ __forceinline__ void gl2lds16(const void* g, void* l) {
    __builtin_amdgcn_global_load_lds((GLOBAL_AS const void*)g, (LDS_AS void*)l, 16, 0, 0);
}

// ---------- prep: fp32->bf16 convert (blocks 0..24575) + Asym (rest) ----------
__global__ void k_prep(const float* __restrict__ batch, const float* __restrict__ proj,
                       bf16_t* __restrict__ Hb, bf16_t* __restrict__ Ab) {
    int bid = blockIdx.x;
    if (bid < 24576) {
        int gid = bid * 256 + threadIdx.x;       // < 6291456 exactly
        const float4* xp = (const float4*)batch;
        float4 a = xp[gid * 2];
        float4 b = xp[gid * 2 + 1];
        bf16x8 v;
        v[0] = (bf16_t)a.x; v[1] = (bf16_t)a.y; v[2] = (bf16_t)a.z; v[3] = (bf16_t)a.w;
        v[4] = (bf16_t)b.x; v[5] = (bf16_t)b.y; v[6] = (bf16_t)b.z; v[7] = (bf16_t)b.w;
        ((bf16x8*)Hb)[gid] = v;
    } else {
        int idx = (bid - 24576) * 256 + threadIdx.x;  // < 589824 = 768^2 exactly
        int d = idx / DIM;
        int e = idx - d * DIM;
        Ab[idx] = (bf16_t)(proj[idx] + proj[e * DIM + d]);
    }
}

// ---------------- GEMM1: M = H @ Asym (no q fusion — atomics regressed) ------
// XCD-affine: xcd g&7 owns contiguous row-slab range; Asym (1.2 MB) L2-resident.
__global__ void k_gemm1(const bf16_t* __restrict__ H, const bf16_t* __restrict__ Ag,
                        bf16_t* __restrict__ M) {
    __shared__ bf16_t Asm[128 * 32];
    __shared__ bf16_t Bsm[128 * 32];
    const int t = threadIdx.x;
    const int g = blockIdx.x;
    const int tile = (g & 7) * 384 + (g >> 3);   // 3072/8 = 384 tiles per XCD
    const int row0 = (tile / 6) * 128;
    const int col0 = (tile % 6) * 128;
    const int ln = t & 63, w = t >> 6;
    const int wr = w >> 1, wc = w & 1;
    const int r = ln & 15, qd = ln >> 4;
    const int sseg = qd ^ ((r >> 1) & 3);        // swizzled read segment

    const int srow = t >> 2;
    const int gseg = (t & 3) ^ ((t >> 3) & 3);   // swizzled global segment
    const bf16_t* gA0 = H  + (size_t)(row0 + srow) * DIM + gseg * 8;
    const bf16_t* gA1 = gA0 + (size_t)64 * DIM;
    const bf16_t* gB0 = Ag + (size_t)(col0 + srow) * DIM + gseg * 8;
    const bf16_t* gB1 = gB0 + (size_t)64 * DIM;

    f32x4 acc[4][4] = {};

    for (int k0 = 0; k0 < DIM; k0 += 32) {
        gl2lds16(gA0 + k0, &Asm[t * 8]);
        gl2lds16(gA1 + k0, &Asm[2048 + t * 8]);
        gl2lds16(gB0 + k0, &Bsm[t * 8]);
        gl2lds16(gB1 + k0, &Bsm[2048 + t * 8]);
        __syncthreads();

        bf16x8 af[4], bf[4];
#pragma unroll
        for (int mt = 0; mt < 4; ++mt) {
            int m = wr * 64 + mt * 16 + r;
            af[mt] = *(const bf16x8*)&Asm[m * 32 + sseg * 8];
        }
#pragma unroll
        for (int nt = 0; nt < 4; ++nt) {
            int n = wc * 64 + nt * 16 + r;
            bf[nt] = *(const bf16x8*)&Bsm[n * 32 + sseg * 8];
        }
#pragma unroll
        for (int mt = 0; mt < 4; ++mt)
#pragma unroll
            for (int nt = 0; nt < 4; ++nt)
                acc[mt][nt] = __builtin_amdgcn_mfma_f32_16x16x32_bf16(
                    af[mt], bf[nt], acc[mt][nt], 0, 0, 0);
        __syncthreads();
    }

#pragma unroll
    for (int mt = 0; mt < 4; ++mt) {
#pragma unroll
        for (int rI = 0; rI < 4; ++rI) {
            int row = row0 + wr * 64 + mt * 16 + qd * 4 + rI;
            size_t base = (size_t)row * DIM + col0 + wc * 64;
#pragma unroll
            for (int nt = 0; nt < 4; ++nt)
                M[base + nt * 16 + r] = (bf16_t)acc[mt][nt][rI];
        }
    }
}

// ---------------- GEMM2 diagonal: tile (b,ti,ti) + fused q, no atomics -------
// A-tile = M[rows][k], B-tile = H[same rows][k]: thread t's two staged bf16x8
// vectors (same swizzled (row,k) slots in Asm and Bsm) give q[row] partials for
// free. Each block exclusively owns its 128 rows -> plain qv stores.
__global__ void k_g2diag(const bf16_t* __restrict__ M, const bf16_t* __restrict__ H,
                         float* __restrict__ qv, float* __restrict__ out) {
    __shared__ bf16_t Asm[128 * 32];
    __shared__ bf16_t Bsm[128 * 32];
    __shared__ float qsm[128];
    const int t = threadIdx.x;
    const int g = blockIdx.x;                    // 0..511
    const int u = (g & 7) * 64 + (g >> 3);       // 8 batches per XCD
    const int b = u >> 3;
    const int ti = u & 7;
    const int row0 = ti * 128;

    const int ln = t & 63, w = t >> 6;
    const int wr = w >> 1, wc = w & 1;
    const int r = ln & 15, qd = ln >> 4;
    const int sseg = qd ^ ((r >> 1) & 3);

    const bf16_t* Mb = M + (size_t)b * SEQ * DIM;
    const bf16_t* Hb = H + (size_t)b * SEQ * DIM;

    const int srow = t >> 2;
    const int gseg = (t & 3) ^ ((t >> 3) & 3);
    const bf16_t* gA0 = Mb + (size_t)(row0 + srow) * DIM + gseg * 8;
    const bf16_t* gA1 = gA0 + (size_t)64 * DIM;
    const bf16_t* gB0 = Hb + (size_t)(row0 + srow) * DIM + gseg * 8;
    const bf16_t* gB1 = gB0 + (size_t)64 * DIM;

    f32x4 acc[4][4] = {};
    float s0 = 0.f, s1 = 0.f;                    // q partials: rows srow, 64+srow

    for (int k0 = 0; k0 < DIM; k0 += 32) {
        gl2lds16(gA0 + k0, &Asm[t * 8]);
        gl2lds16(gA1 + k0, &Asm[2048 + t * 8]);
        gl2lds16(gB0 + k0, &Bsm[t * 8]);
        gl2lds16(gB1 + k0, &Bsm[2048 + t * 8]);
        __syncthreads();

        // fused q: dot of this thread's own staged vectors (elementwise-aligned)
        bf16x8 va0 = *(const bf16x8*)&Asm[t * 8];
        bf16x8 vb0 = *(const bf16x8*)&Bsm[t * 8];
        bf16x8 va1 = *(const bf16x8*)&Asm[2048 + t * 8];
        bf16x8 vb1 = *(const bf16x8*)&Bsm[2048 + t * 8];
#pragma unroll
        for (int j = 0; j < 8; ++j) {
            s0 += (float)va0[j] * (float)vb0[j];
            s1 += (float)va1[j] * (float)vb1[j];
        }

        bf16x8 af[4], bfv[4];
#pragma unroll
        for (int mt = 0; mt < 4; ++mt) {
            int m = wr * 64 + mt * 16 + r;
            af[mt] = *(const bf16x8*)&Asm[m * 32 + sseg * 8];
        }
#pragma unroll
        for (int nt = 0; nt < 4; ++nt) {
            int n = wc * 64 + nt * 16 + r;
            bfv[nt] = *(const bf16x8*)&Bsm[n * 32 + sseg * 8];
        }
#pragma unroll
        for (int mt = 0; mt < 4; ++mt)
#pragma unroll
            for (int nt = 0; nt < 4; ++nt)
                acc[mt][nt] = __builtin_amdgcn_mfma_f32_16x16x32_bf16(
                    af[mt], bfv[nt], acc[mt][nt], 0, 0, 0);
        __syncthreads();
    }

    // reduce q over the 4 segment-threads of each row (lanes 4k..4k+3)
    s0 += __shfl_xor(s0, 1, 64); s0 += __shfl_xor(s0, 2, 64);
    s1 += __shfl_xor(s1, 1, 64); s1 += __shfl_xor(s1, 2, 64);
    if ((t & 3) == 0) {
        float q0 = 0.5f * s0, q1 = 0.5f * s1;
        qsm[srow] = q0; qsm[64 + srow] = q1;
        qv[(size_t)b * SEQ + row0 + srow] = q0;
        qv[(size_t)b * SEQ + row0 + 64 + srow] = q1;
    }
    __syncthreads();

    float qc[4];
#pragma unroll
    for (int nt = 0; nt < 4; ++nt) qc[nt] = qsm[wc * 64 + nt * 16 + r];

#pragma unroll
    for (int mt = 0; mt < 4; ++mt) {
#pragma unroll
        for (int rI = 0; rI < 4; ++rI) {
            int lrow = wr * 64 + mt * 16 + qd * 4 + rI;
            float qr = qsm[lrow];
            size_t base = ((size_t)b * SEQ + row0 + lrow) * SEQ + row0 + wc * 64;
#pragma unroll
            for (int nt = 0; nt < 4; ++nt)
                out[base + nt * 16 + r] = qr + qc[nt] - acc[mt][nt][rI];
        }
    }
}

// ---------------- GEMM2 off-diagonal: ti<tj, mirrored write ----------------
__global__ void k_g2off(const bf16_t* __restrict__ M, const bf16_t* __restrict__ H,
                        const float* __restrict__ qv, float* __restrict__ out) {
    __shared__ __align__(16) char smem[16640];   // max(2*8192, 32*130*4)
    bf16_t* Asm = (bf16_t*)smem;
    bf16_t* Bsm = (bf16_t*)(smem + 8192);
    float*  Tsm = (float*)smem;                  // 32 x 130 fp32 transpose chunk

    const int t = threadIdx.x;
    const int g = blockIdx.x;                    // 0..1791
    const int u = (g & 7) * 224 + (g >> 3);      // 8 batches per XCD
    const int b = u / 28;
    int l = u - b * 28;
    int ti = 0;
    while (l >= 7 - ti) { l -= 7 - ti; ++ti; }   // uniform scalar decode, ti<tj
    const int tj = ti + 1 + l;
    const int row0 = ti * 128;
    const int col0 = tj * 128;

    const int ln = t & 63, w = t >> 6;
    const int wr = w >> 1, wc = w & 1;
    const int r = ln & 15, qd = ln >> 4;
    const int sseg = qd ^ ((r >> 1) & 3);

    const bf16_t* Mb = M + (size_t)b * SEQ * DIM;
    const bf16_t* Hb = H + (size_t)b * SEQ * DIM;

    const int srow = t >> 2;
    const int gseg = (t & 3) ^ ((t >> 3) & 3);
    const bf16_t* gA0 = Mb + (size_t)(row0 + srow) * DIM + gseg * 8;
    const bf16_t* gA1 = gA0 + (size_t)64 * DIM;
    const bf16_t* gB0 = Hb + (size_t)(col0 + srow) * DIM + gseg * 8;
    const bf16_t* gB1 = gB0 + (size_t)64 * DIM;

    f32x4 acc[4][4] = {};

    for (int k0 = 0; k0 < DIM; k0 += 32) {
        gl2lds16(gA0 + k0, &Asm[t * 8]);
        gl2lds16(gA1 + k0, &Asm[2048 + t * 8]);
        gl2lds16(gB0 + k0, &Bsm[t * 8]);
        gl2lds16(gB1 + k0, &Bsm[2048 + t * 8]);
        __syncthreads();

        bf16x8 af[4], bfv[4];
#pragma unroll
        for (int mt = 0; mt < 4; ++mt) {
            int m = wr * 64 + mt * 16 + r;
            af[mt] = *(const bf16x8*)&Asm[m * 32 + sseg * 8];
        }
#pragma unroll
        for (int nt = 0; nt < 4; ++nt) {
            int n = wc * 64 + nt * 16 + r;
            bfv[nt] = *(const bf16x8*)&Bsm[n * 32 + sseg * 8];
        }
#pragma unroll
        for (int mt = 0; mt < 4; ++mt)
#pragma unroll
            for (int nt = 0; nt < 4; ++nt)
                acc[mt][nt] = __builtin_amdgcn_mfma_f32_16x16x32_bf16(
                    af[mt], bfv[nt], acc[mt][nt], 0, 0, 0);
        __syncthreads();
    }

    const float* qb = qv + (size_t)b * SEQ;
    float qc[4];
#pragma unroll
    for (int nt = 0; nt < 4; ++nt) qc[nt] = qb[col0 + wc * 64 + nt * 16 + r];

    // upper tile write: out[b][row][col]
#pragma unroll
    for (int mt = 0; mt < 4; ++mt) {
#pragma unroll
        for (int rI = 0; rI < 4; ++rI) {
            int row = row0 + wr * 64 + mt * 16 + qd * 4 + rI;
            float qr = qb[row];
            size_t base = ((size_t)b * SEQ + row) * SEQ + col0 + wc * 64;
#pragma unroll
            for (int nt = 0; nt < 4; ++nt)
                out[base + nt * 16 + r] = qr + qc[nt] - acc[mt][nt][rI];
        }
    }

    // mirror (lower) tile write: out[b][col][row], via 4x 32-row LDS chunks.
#pragma unroll
    for (int c = 0; c < 4; ++c) {
        __syncthreads();                        // prev chunk fully consumed
        if (wr == (c >> 1)) {
            const int m0 = (c & 1) * 2;         // compile-time per unrolled c
#pragma unroll
            for (int mi = 0; mi < 2; ++mi) {
                const int mt = m0 + mi;         // static index into acc
#pragma unroll
                for (int rI = 0; rI < 4; ++rI) {
                    int lrow = mi * 16 + qd * 4 + rI;          // 0..31
                    int row = row0 + wr * 64 + mt * 16 + qd * 4 + rI;
                    float qr = qb[row];
#pragma unroll
                    for (int nt = 0; nt < 4; ++nt) {
                        int lcol = wc * 64 + nt * 16 + r;
                        Tsm[lrow * 130 + lcol] = qr + qc[nt] - acc[mt][nt][rI];
                    }
                }
            }
        }
        __syncthreads();
        const int rowbase = row0 + 32 * c;
#pragma unroll
        for (int i = 0; i < 16; ++i) {
            int lin = i * 256 + t;
            int lrow = lin & 31;
            int lcol = lin >> 5;                // 0..127
            out[((size_t)b * SEQ + col0 + lcol) * SEQ + rowbase + lrow] =
                Tsm[lrow * 130 + lcol];
        }
    }
}

extern "C" void kernel_launch(void* const* d_in, const int* in_sizes, int n_in,
                              void* d_out, int out_size, void* d_ws, size_t ws_size,
                              hipStream_t stream) {
    const float* batch = (const float*)d_in[0];  // (64,1024,768) fp32
    const float* proj  = (const float*)d_in[1];  // (768,768) fp32
    float* out = (float*)d_out;                  // (64,1024,1024) fp32

    char* ws = (char*)d_ws;
    // Workspace layout (all 16B-aligned):
    //   Hb:  BS_ROWS*DIM bf16  = 100663296 B  @ 0
    //   Mb:  BS_ROWS*DIM bf16  = 100663296 B  @ 100663296
    //   Ab:  DIM*DIM bf16      =   1179648 B  @ 201326592
    //   qv:  BS_ROWS fp32      =    262144 B  @ 202506240
    bf16_t* Hb = (bf16_t*)ws;
    bf16_t* Mb = (bf16_t*)(ws + 100663296);
    bf16_t* Ab = (bf16_t*)(ws + 201326592);
    float*  qv = (float*)(ws + 202506240);

    // 1) batch -> bf16 (24576 blocks) + Asym = A + A^T (2304 blocks), fused
    k_prep<<<26880, 256, 0, stream>>>(batch, proj, Hb, Ab);
    // 2) M = H @ Asym   (65536 x 768, K=768)
    k_gemm1<<<3072, 256, 0, stream>>>(Hb, Ab, Mb);
    // 3) diagonal tiles of dists + q (plain stores, block owns its rows)
    k_g2diag<<<512, 256, 0, stream>>>(Mb, Hb, qv, out);
    // 4) off-diagonal tiles (ti<tj), reads qv, mirrored write
    k_g2off<<<1792, 256, 0, stream>>>(Mb, Hb, qv, out);
}